// Round 14
// baseline (197.495 us; speedup 1.0000x reference)
//
#include <hip/hip_runtime.h>

#define B_ 2
#define N_ 4096
#define M_ 2048
#define D_ 256
#define H_ 8
#define DH_ 32
#define ROWS_ (B_*N_)
#define KVROWS_ (B_*M_)
#define QSCALE_ 0.17677669529663687f
// bias folded into QK accumulator init: 32*ln2 (any constant works; cancels in O/l)
#define ZB_ 22.18070977791825f

typedef __attribute__((ext_vector_type(8))) short short8_t;
typedef __attribute__((ext_vector_type(4))) float float4_t;

__device__ __forceinline__ float us2f(unsigned short s) {
    union { unsigned int u; float f; } c;
    c.u = ((unsigned int)s) << 16;
    return c.f;
}

__device__ __forceinline__ unsigned short f2us(float f) {
    union { float f; unsigned int u; } c;
    c.f = f;
    unsigned int u = c.u;
    unsigned int r = u + 0x7FFFu + ((u >> 16) & 1u);  // RTNE
    return (unsigned short)(r >> 16);
}

__device__ __forceinline__ unsigned int pack2rn(float a, float b) {
    return (unsigned int)f2us(a) | ((unsigned int)f2us(b) << 16);
}

// truncation pack (P tiles / MFMA A-frags; <=2^-8 rel err)
__device__ __forceinline__ unsigned int pack2tr(float a, float b) {
    union { float f; unsigned int u; } x, y;
    x.f = a; y.f = b;
    return (x.u >> 16) | (y.u & 0xFFFF0000u);
}

__device__ __forceinline__ short8_t cvt8(float4 a, float4 b) {
    union { unsigned int u[4]; short8_t s; } c;
    c.u[0] = pack2rn(a.x, a.y);
    c.u[1] = pack2rn(a.z, a.w);
    c.u[2] = pack2rn(b.x, b.y);
    c.u[3] = pack2rn(b.z, b.w);
    return c.s;
}

__device__ __forceinline__ short8_t cvt8tr(const float* v) {
    union { unsigned int u[4]; short8_t s; } c;
    c.u[0] = pack2tr(v[0], v[1]);
    c.u[1] = pack2tr(v[2], v[3]);
    c.u[2] = pack2tr(v[4], v[5]);
    c.u[3] = pack2tr(v[6], v[7]);
    return c.s;
}

// ---------------------------------------------------------------------------
// Stage NCOL x K fp32 weight block into XOR-swizzled bf16 LDS.
// ---------------------------------------------------------------------------
template<int K, int NCOL>
__device__ __forceinline__ void stageB(const float* __restrict__ W, int col0,
                                       unsigned short* __restrict__ Bs, int tid)
{
    const int n = tid & (NCOL - 1), g = tid / NCOL;
    const int GROUPS = 256 / NCOL;
    const int CPT = (K / 8) / GROUPS;
    const float* src = W + (size_t)(col0 + n) * K + g * (K / GROUPS);
#pragma unroll
    for (int ci = 0; ci < CPT; ci++) {
        int logc = g * CPT + ci;
        int phys = logc ^ (n & 7);
        short8_t v = cvt8(*(const float4*)(src + ci * 8), *(const float4*)(src + ci * 8 + 4));
        *(short8_t*)(Bs + (size_t)n * K + phys * 8) = v;
    }
}

template<int K>
__device__ __forceinline__ short8_t readB(const unsigned short* __restrict__ Bs,
                                          int c, int l16, int quad, int k0)
{
    int phys = ((k0 >> 3) + quad) ^ (l16 & 7);
    return *(const short8_t*)(Bs + (size_t)(16 * c + l16) * K + phys * 8);
}

// ---------------------------------------------------------------------------
// Merged projection kernel (unchanged structure; q now scaled by QSCALE_ only).
// ---------------------------------------------------------------------------
__global__ __launch_bounds__(256) void g_proj(
    const float* __restrict__ points, const float* __restrict__ voxel,
    const float* __restrict__ Wp, const float* __restrict__ bp,
    const float* __restrict__ Wq, const float* __restrict__ bq,
    const float* __restrict__ Wk, const float* __restrict__ bk,
    const float* __restrict__ Wv, const float* __restrict__ bv,
    unsigned short* __restrict__ pf_g, unsigned short* __restrict__ q_g,
    unsigned short* __restrict__ k_g, unsigned short* __restrict__ vt_g)
{
    const int tid = threadIdx.x;
    const int wave = tid >> 6, lane = tid & 63, quad = lane >> 4, l16 = lane & 15;

    __shared__ unsigned short Bs[64 * 256];  // 32 KB
    __shared__ float Wp_lds[256 * 5];        //  5 KB

    if (blockIdx.x < 512) {
        const int row0 = ((int)blockIdx.x >> 2) * 64;
        const int col0 = ((int)blockIdx.x & 3) * 64;
        stageB<256, 64>(Wq, col0, Bs, tid);
        Wp_lds[tid * 5 + 0] = Wp[tid * 3 + 0];
        Wp_lds[tid * 5 + 1] = Wp[tid * 3 + 1];
        Wp_lds[tid * 5 + 2] = Wp[tid * 3 + 2];
        Wp_lds[tid * 5 + 3] = bp[tid];
        __syncthreads();

        const int n = row0 + wave * 16 + l16;
        const float p0 = points[(size_t)n * 3 + 0];
        const float p1 = points[(size_t)n * 3 + 1];
        const float p2 = points[(size_t)n * 3 + 2];

        float4_t acc[4];
#pragma unroll
        for (int c = 0; c < 4; c++) acc[c] = (float4_t){0.f, 0.f, 0.f, 0.f};

#pragma unroll
        for (int k0 = 0; k0 < 256; k0 += 32) {
            float pf[8];
#pragma unroll
            for (int j = 0; j < 8; j++) {
                int c = k0 + quad * 8 + j;
                pf[j] = p0 * Wp_lds[c * 5 + 0] + p1 * Wp_lds[c * 5 + 1]
                      + p2 * Wp_lds[c * 5 + 2] + Wp_lds[c * 5 + 3];
            }
            short8_t af = cvt8(make_float4(pf[0], pf[1], pf[2], pf[3]),
                               make_float4(pf[4], pf[5], pf[6], pf[7]));
            if (col0 == 0)
                *(short8_t*)(pf_g + (size_t)n * D_ + k0 + quad * 8) = af;
#pragma unroll
            for (int c = 0; c < 4; c++)
                acc[c] = __builtin_amdgcn_mfma_f32_16x16x32_bf16(af, readB<256>(Bs, c, l16, quad, k0), acc[c], 0, 0, 0);
        }
#pragma unroll
        for (int c = 0; c < 4; c++) {
            int col = col0 + 16 * c + l16;
            float bb = bq[col];
#pragma unroll
            for (int r = 0; r < 4; r++) {
                int row = row0 + wave * 16 + quad * 4 + r;
                q_g[(size_t)row * D_ + col] = f2us((acc[c][r] + bb) * QSCALE_);
            }
        }
    } else {
        const int bid = (int)blockIdx.x - 512;
        const int row0 = (bid >> 2) * 64;
        const int col0 = (bid & 3) * 64;
        const float* arow = voxel + (size_t)(row0 + wave * 16 + l16) * D_;

        float4_t ak[4], av[4];
#pragma unroll
        for (int c = 0; c < 4; c++) {
            ak[c] = (float4_t){0.f, 0.f, 0.f, 0.f};
            av[c] = (float4_t){0.f, 0.f, 0.f, 0.f};
        }
        stageB<256, 64>(Wk, col0, Bs, tid);
        __syncthreads();
#pragma unroll
        for (int k0 = 0; k0 < 256; k0 += 32) {
            short8_t af = cvt8(*(const float4*)(arow + k0 + quad * 8),
                               *(const float4*)(arow + k0 + quad * 8 + 4));
#pragma unroll
            for (int c = 0; c < 4; c++)
                ak[c] = __builtin_amdgcn_mfma_f32_16x16x32_bf16(af, readB<256>(Bs, c, l16, quad, k0), ak[c], 0, 0, 0);
        }
        __syncthreads();
        stageB<256, 64>(Wv, col0, Bs, tid);
        __syncthreads();
#pragma unroll
        for (int k0 = 0; k0 < 256; k0 += 32) {
            short8_t af = cvt8(*(const float4*)(arow + k0 + quad * 8),
                               *(const float4*)(arow + k0 + quad * 8 + 4));
#pragma unroll
            for (int c = 0; c < 4; c++)
                av[c] = __builtin_amdgcn_mfma_f32_16x16x32_bf16(af, readB<256>(Bs, c, l16, quad, k0), av[c], 0, 0, 0);
        }
        const int b = row0 / M_;
        const int m0 = row0 - b * M_ + wave * 16 + quad * 4;
#pragma unroll
        for (int c = 0; c < 4; c++) {
            int col = col0 + 16 * c + l16;
            float bbk = bk[col], bbv = bv[col];
#pragma unroll
            for (int r = 0; r < 4; r++) {
                int row = row0 + wave * 16 + quad * 4 + r;
                k_g[(size_t)row * D_ + col] = f2us(ak[c][r] + bbk);
            }
            int h = col >> 5, dh = col & 31;
            unsigned int u0 = pack2rn(av[c][0] + bbv, av[c][1] + bbv);
            unsigned int u1 = pack2rn(av[c][2] + bbv, av[c][3] + bbv);
            *(uint2*)(vt_g + (size_t)((b * H_ + h) * DH_ + dh) * M_ + m0) = make_uint2(u0, u1);
        }
    }
}

// ---------------------------------------------------------------------------
// MFMA flash attention, cooperative dbuf staging, native __expf softmax.
// MODE 0: grid 1024, full kv range, normalized bf16 att out (r13 fallback).
// MODE 1: grid 2048, kv-split x2 (half = bid&1); writes UNNORMALIZED bf16 O
//         partial + fp32 l partial; combine folded into g_fuse.
// ---------------------------------------------------------------------------
template<int MODE>
__global__ __launch_bounds__(256) void k_attn7(
    const unsigned short* __restrict__ q_g,
    const unsigned short* __restrict__ k_g,
    const unsigned short* __restrict__ vt_g,
    unsigned short* __restrict__ o0_g,
    unsigned short* __restrict__ o1_g,
    float* __restrict__ lsum)
{
    const int tid = threadIdx.x;
    const int w = tid >> 6, lane = tid & 63, quad = lane >> 4, l16 = lane & 15;
    const int bid = blockIdx.x;
    const int half = (MODE == 1) ? (bid & 1) : 0;
    const int rest = (MODE == 1) ? (bid >> 1) : bid;
    const int nt = rest & 63;
    const int bh = rest >> 6;
    const int b = bh >> 3, h = bh & 7;
    const int n0 = nt * 64 + w * 16;
    const int kvbeg = half * (M_ / 2);
    const int NSTEP = (MODE == 1) ? (M_ / 128) * 2 : M_ / 64;  // 16 or 32

    __shared__ unsigned short Kt[2][64][40];
    __shared__ unsigned short Vt[2][32][72];
    __shared__ unsigned short Pb[4][16][64];

    short8_t qf = *(const short8_t*)(q_g + (size_t)(b * N_ + n0 + l16) * D_ + h * DH_ + quad * 8);

    float4_t od0 = {0.f, 0.f, 0.f, 0.f};
    float4_t od1 = {0.f, 0.f, 0.f, 0.f};
    float l_lane = 0.f;

    const unsigned short* kbase = k_g + (size_t)(b * M_) * D_ + h * DH_;
    const unsigned short* vbase = vt_g + (size_t)(bh * DH_) * M_;
    unsigned short* pb = &Pb[w][0][0];
    const int h7 = l16 & 7;
    const float4_t zc = {-ZB_, -ZB_, -ZB_, -ZB_};

    const int kr = tid >> 2, kc = tid & 3;
    const int vr = tid >> 3, vc = tid & 7;

    *(short8_t*)&Kt[0][kr][kc * 8] = *(const short8_t*)(kbase + (size_t)(kvbeg + kr) * D_ + kc * 8);
    *(short8_t*)&Vt[0][vr][vc * 8] = *(const short8_t*)(vbase + (size_t)vr * M_ + kvbeg + vc * 8);

    for (int s = 0; s < NSTEP; s++) {
        __syncthreads();
        const int buf = s & 1;
        const int kv0 = kvbeg + s * 64;
        if (s + 1 < NSTEP) {
            const int kv1 = kv0 + 64;
            *(short8_t*)&Kt[buf ^ 1][kr][kc * 8] =
                *(const short8_t*)(kbase + (size_t)(kv1 + kr) * D_ + kc * 8);
            *(short8_t*)&Vt[buf ^ 1][vr][vc * 8] =
                *(const short8_t*)(vbase + (size_t)vr * M_ + kv1 + vc * 8);
        }

        float4_t st[4];
#pragma unroll
        for (int t = 0; t < 4; t++) {
            short8_t kf = *(const short8_t*)&Kt[buf][16 * t + l16][quad * 8];
            st[t] = __builtin_amdgcn_mfma_f32_16x16x32_bf16(kf, qf, zc, 0, 0, 0);
        }

        float psum = 0.f;
#pragma unroll
        for (int t = 0; t < 4; t++) {
            float p0 = __expf(st[t][0]);
            float p1 = __expf(st[t][1]);
            float p2 = __expf(st[t][2]);
            float p3 = __expf(st[t][3]);
            psum += (p0 + p1) + (p2 + p3);
            unsigned int u0 = pack2tr(p0, p1);
            unsigned int u1 = pack2tr(p2, p3);
            int phys = (2 * t + (quad >> 1)) ^ h7;
            *(uint2*)(pb + l16 * 64 + phys * 8 + (quad & 1) * 4) = make_uint2(u0, u1);
        }
        l_lane += psum;

        short8_t pfa = *(const short8_t*)(pb + l16 * 64 + (quad ^ h7) * 8);
        short8_t pfb = *(const short8_t*)(pb + l16 * 64 + ((4 + quad) ^ h7) * 8);

        short8_t vf00 = *(const short8_t*)&Vt[buf][l16][quad * 8];
        short8_t vf01 = *(const short8_t*)&Vt[buf][l16][32 + quad * 8];
        short8_t vf10 = *(const short8_t*)&Vt[buf][16 + l16][quad * 8];
        short8_t vf11 = *(const short8_t*)&Vt[buf][16 + l16][32 + quad * 8];
        od0 = __builtin_amdgcn_mfma_f32_16x16x32_bf16(vf00, pfa, od0, 0, 0, 0);
        od0 = __builtin_amdgcn_mfma_f32_16x16x32_bf16(vf01, pfb, od0, 0, 0, 0);
        od1 = __builtin_amdgcn_mfma_f32_16x16x32_bf16(vf10, pfa, od1, 0, 0, 0);
        od1 = __builtin_amdgcn_mfma_f32_16x16x32_bf16(vf11, pfb, od1, 0, 0, 0);
    }

    l_lane += __shfl_xor(l_lane, 16);
    l_lane += __shfl_xor(l_lane, 32);

    if (MODE == 0) {
        const float inv = 1.0f / l_lane;
        unsigned short* ob = o0_g + (size_t)(b * N_ + n0 + l16) * D_ + h * DH_;
        unsigned int u0 = pack2rn(od0[0] * inv, od0[1] * inv);
        unsigned int u1 = pack2rn(od0[2] * inv, od0[3] * inv);
        *(uint2*)(ob + quad * 4) = make_uint2(u0, u1);
        unsigned int u2 = pack2rn(od1[0] * inv, od1[1] * inv);
        unsigned int u3 = pack2rn(od1[2] * inv, od1[3] * inv);
        *(uint2*)(ob + 16 + quad * 4) = make_uint2(u2, u3);
    } else {
        const int row = b * N_ + n0 + l16;
        if (quad == 0) lsum[(size_t)half * ROWS_ * H_ + (size_t)row * H_ + h] = l_lane;
        unsigned short* ob = (half ? o1_g : o0_g) + (size_t)row * D_ + h * DH_;
        unsigned int u0 = pack2rn(od0[0], od0[1]);
        unsigned int u1 = pack2rn(od0[2], od0[3]);
        *(uint2*)(ob + quad * 4) = make_uint2(u0, u1);
        unsigned int u2 = pack2rn(od1[0], od1[1]);
        unsigned int u3 = pack2rn(od1[2], od1[3]);
        *(uint2*)(ob + 16 + quad * 4) = make_uint2(u2, u3);
    }
}

// ---------------------------------------------------------------------------
// MFMA GEMM: out = concat(pf, att) @ Wf.T + bf, fp32 out. 64x32 tiles.
// MODE 1: att A-frags combined inline from partials: (o0+o1)/(l0+l1).
// ---------------------------------------------------------------------------
template<int MODE>
__global__ __launch_bounds__(256) void g_fuse(
    const unsigned short* __restrict__ pf_g,
    const unsigned short* __restrict__ o0_g,
    const unsigned short* __restrict__ o1_g,
    const float* __restrict__ lsum,
    const float* __restrict__ Wf, const float* __restrict__ bfb,
    float* __restrict__ out)
{
    const int tid = threadIdx.x;
    const int wave = tid >> 6, lane = tid & 63, quad = lane >> 4, l16 = lane & 15;
    const int row0 = ((int)blockIdx.x >> 3) * 64;
    const int col0 = ((int)blockIdx.x & 7) * 32;

    __shared__ unsigned short Bs[32 * 512];  // 32 KB

    stageB<512, 32>(Wf, col0, Bs, tid);
    __syncthreads();

    float4_t acc[2];
#pragma unroll
    for (int c = 0; c < 2; c++) acc[c] = (float4_t){0.f, 0.f, 0.f, 0.f};

    const int arow_i = row0 + wave * 16 + l16;
    const size_t arow = (size_t)arow_i * D_;
#pragma unroll
    for (int k0 = 0; k0 < 512; k0 += 32) {
        short8_t af;
        if (k0 < 256) {
            af = *(const short8_t*)(pf_g + arow + k0 + quad * 8);
        } else if (MODE == 0) {
            af = *(const short8_t*)(o0_g + arow + (k0 - 256) + quad * 8);
        } else {
            const int co = k0 - 256 + quad * 8;
            const int h = (k0 - 256) >> 5;
            short8_t a0 = *(const short8_t*)(o0_g + arow + co);
            short8_t a1 = *(const short8_t*)(o1_g + arow + co);
            float l0 = lsum[(size_t)arow_i * H_ + h];
            float l1 = lsum[(size_t)ROWS_ * H_ + (size_t)arow_i * H_ + h];
            float inv = 1.0f / (l0 + l1);
            float v[8];
#pragma unroll
            for (int j = 0; j < 8; j++)
                v[j] = (us2f((unsigned short)a0[j]) + us2f((unsigned short)a1[j])) * inv;
            af = cvt8tr(v);
        }
#pragma unroll
        for (int c = 0; c < 2; c++)
            acc[c] = __builtin_amdgcn_mfma_f32_16x16x32_bf16(af, readB<512>(Bs, c, l16, quad, k0), acc[c], 0, 0, 0);
    }
#pragma unroll
    for (int c = 0; c < 2; c++) {
        int col = col0 + 16 * c + l16;
        float bb = bfb[col];
#pragma unroll
        for (int r = 0; r < 4; r++) {
            int row = row0 + wave * 16 + quad * 4 + r;
            out[(size_t)row * D_ + col] = acc[c][r] + bb;
        }
    }
}

// ---------------------------------------------------------------------------
extern "C" void kernel_launch(void* const* d_in, const int* in_sizes, int n_in,
                              void* d_out, int out_size, void* d_ws, size_t ws_size,
                              hipStream_t stream)
{
    const float* points = (const float*)d_in[0];
    const float* voxel  = (const float*)d_in[1];
    const float* Wp  = (const float*)d_in[2];
    const float* bp  = (const float*)d_in[3];
    const float* Wq  = (const float*)d_in[4];
    const float* bq  = (const float*)d_in[5];
    const float* Wk  = (const float*)d_in[6];
    const float* bk  = (const float*)d_in[7];
    const float* Wv  = (const float*)d_in[8];
    const float* bv  = (const float*)d_in[9];
    const float* Wf  = (const float*)d_in[10];
    const float* bfb = (const float*)d_in[11];
    float* out = (float*)d_out;

    unsigned short* ws = (unsigned short*)d_ws;
    unsigned short* pf_g = ws;                               // ROWS*D
    unsigned short* q_g  = pf_g + (size_t)ROWS_ * D_;
    unsigned short* k_g  = q_g  + (size_t)ROWS_ * D_;
    unsigned short* vt_g = k_g  + (size_t)KVROWS_ * D_;
    unsigned short* o0_g = vt_g + (size_t)KVROWS_ * D_;      // att or partial 0
    unsigned short* o1_g = o0_g + (size_t)ROWS_ * D_;        // partial 1 (split)
    float* lsum = (float*)(o1_g + (size_t)ROWS_ * D_);       // [2][ROWS][H]

    const size_t need_split = ((size_t)ROWS_ * D_ * 4 + (size_t)KVROWS_ * D_ * 2) * 2
                            + (size_t)ROWS_ * H_ * 2 * sizeof(float);

    g_proj<<<dim3(768), dim3(256), 0, stream>>>(points, voxel, Wp, bp, Wq, bq,
                                                Wk, bk, Wv, bv, pf_g, q_g, k_g, vt_g);
    if (ws_size >= need_split) {
        k_attn7<1><<<dim3(2 * B_ * H_ * (N_ / 64)), dim3(256), 0, stream>>>(
            q_g, k_g, vt_g, o0_g, o1_g, lsum);
        g_fuse<1><<<dim3((ROWS_ / 64) * 8), dim3(256), 0, stream>>>(
            pf_g, o0_g, o1_g, lsum, Wf, bfb, out);
    } else {
        k_attn7<0><<<dim3(B_ * H_ * (N_ / 64)), dim3(256), 0, stream>>>(
            q_g, k_g, vt_g, o0_g, o1_g, lsum);
        g_fuse<0><<<dim3((ROWS_ / 64) * 8), dim3(256), 0, stream>>>(
            pf_g, o0_g, o1_g, lsum, Wf, bfb, out);
    }
}

// Round 15
// 162.003 us; speedup vs baseline: 1.2191x; 1.2191x over previous
//
#include <hip/hip_runtime.h>

#define B_ 2
#define N_ 4096
#define M_ 2048
#define D_ 256
#define H_ 8
#define DH_ 32
#define ROWS_ (B_*N_)
#define KVROWS_ (B_*M_)
#define QSCALE_ 0.17677669529663687f
// bias folded into QK accumulator init: 32*ln2 (any constant works; cancels in O/l)
#define ZB_ 22.18070977791825f

typedef __attribute__((ext_vector_type(8))) short short8_t;
typedef __attribute__((ext_vector_type(4))) float float4_t;

__device__ __forceinline__ float us2f(unsigned short s) {
    union { unsigned int u; float f; } c;
    c.u = ((unsigned int)s) << 16;
    return c.f;
}

__device__ __forceinline__ unsigned short f2us(float f) {
    union { float f; unsigned int u; } c;
    c.f = f;
    unsigned int u = c.u;
    unsigned int r = u + 0x7FFFu + ((u >> 16) & 1u);  // RTNE
    return (unsigned short)(r >> 16);
}

__device__ __forceinline__ unsigned int pack2rn(float a, float b) {
    return (unsigned int)f2us(a) | ((unsigned int)f2us(b) << 16);
}

// truncation pack (P tiles / MFMA A-frags; <=2^-8 rel err)
__device__ __forceinline__ unsigned int pack2tr(float a, float b) {
    union { float f; unsigned int u; } x, y;
    x.f = a; y.f = b;
    return (x.u >> 16) | (y.u & 0xFFFF0000u);
}

__device__ __forceinline__ short8_t cvt8(float4 a, float4 b) {
    union { unsigned int u[4]; short8_t s; } c;
    c.u[0] = pack2rn(a.x, a.y);
    c.u[1] = pack2rn(a.z, a.w);
    c.u[2] = pack2rn(b.x, b.y);
    c.u[3] = pack2rn(b.z, b.w);
    return c.s;
}

__device__ __forceinline__ short8_t cvt8tr(const float* v) {
    union { unsigned int u[4]; short8_t s; } c;
    c.u[0] = pack2tr(v[0], v[1]);
    c.u[1] = pack2tr(v[2], v[3]);
    c.u[2] = pack2tr(v[4], v[5]);
    c.u[3] = pack2tr(v[6], v[7]);
    return c.s;
}

// ---------------------------------------------------------------------------
// Stage NCOL x K fp32 weight block into XOR-swizzled bf16 LDS.
// ---------------------------------------------------------------------------
template<int K, int NCOL>
__device__ __forceinline__ void stageB(const float* __restrict__ W, int col0,
                                       unsigned short* __restrict__ Bs, int tid)
{
    const int n = tid & (NCOL - 1), g = tid / NCOL;
    const int GROUPS = 256 / NCOL;
    const int CPT = (K / 8) / GROUPS;
    const float* src = W + (size_t)(col0 + n) * K + g * (K / GROUPS);
#pragma unroll
    for (int ci = 0; ci < CPT; ci++) {
        int logc = g * CPT + ci;
        int phys = logc ^ (n & 7);
        short8_t v = cvt8(*(const float4*)(src + ci * 8), *(const float4*)(src + ci * 8 + 4));
        *(short8_t*)(Bs + (size_t)n * K + phys * 8) = v;
    }
}

template<int K>
__device__ __forceinline__ short8_t readB(const unsigned short* __restrict__ Bs,
                                          int c, int l16, int quad, int k0)
{
    int phys = ((k0 >> 3) + quad) ^ (l16 & 7);
    return *(const short8_t*)(Bs + (size_t)(16 * c + l16) * K + phys * 8);
}

// ---------------------------------------------------------------------------
// Merged projection kernel (q scaled by QSCALE_ only).
// ---------------------------------------------------------------------------
__global__ __launch_bounds__(256) void g_proj(
    const float* __restrict__ points, const float* __restrict__ voxel,
    const float* __restrict__ Wp, const float* __restrict__ bp,
    const float* __restrict__ Wq, const float* __restrict__ bq,
    const float* __restrict__ Wk, const float* __restrict__ bk,
    const float* __restrict__ Wv, const float* __restrict__ bv,
    unsigned short* __restrict__ pf_g, unsigned short* __restrict__ q_g,
    unsigned short* __restrict__ k_g, unsigned short* __restrict__ vt_g)
{
    const int tid = threadIdx.x;
    const int wave = tid >> 6, lane = tid & 63, quad = lane >> 4, l16 = lane & 15;

    __shared__ unsigned short Bs[64 * 256];  // 32 KB
    __shared__ float Wp_lds[256 * 5];        //  5 KB

    if (blockIdx.x < 512) {
        const int row0 = ((int)blockIdx.x >> 2) * 64;
        const int col0 = ((int)blockIdx.x & 3) * 64;
        stageB<256, 64>(Wq, col0, Bs, tid);
        Wp_lds[tid * 5 + 0] = Wp[tid * 3 + 0];
        Wp_lds[tid * 5 + 1] = Wp[tid * 3 + 1];
        Wp_lds[tid * 5 + 2] = Wp[tid * 3 + 2];
        Wp_lds[tid * 5 + 3] = bp[tid];
        __syncthreads();

        const int n = row0 + wave * 16 + l16;
        const float p0 = points[(size_t)n * 3 + 0];
        const float p1 = points[(size_t)n * 3 + 1];
        const float p2 = points[(size_t)n * 3 + 2];

        float4_t acc[4];
#pragma unroll
        for (int c = 0; c < 4; c++) acc[c] = (float4_t){0.f, 0.f, 0.f, 0.f};

#pragma unroll
        for (int k0 = 0; k0 < 256; k0 += 32) {
            float pf[8];
#pragma unroll
            for (int j = 0; j < 8; j++) {
                int c = k0 + quad * 8 + j;
                pf[j] = p0 * Wp_lds[c * 5 + 0] + p1 * Wp_lds[c * 5 + 1]
                      + p2 * Wp_lds[c * 5 + 2] + Wp_lds[c * 5 + 3];
            }
            short8_t af = cvt8(make_float4(pf[0], pf[1], pf[2], pf[3]),
                               make_float4(pf[4], pf[5], pf[6], pf[7]));
            if (col0 == 0)
                *(short8_t*)(pf_g + (size_t)n * D_ + k0 + quad * 8) = af;
#pragma unroll
            for (int c = 0; c < 4; c++)
                acc[c] = __builtin_amdgcn_mfma_f32_16x16x32_bf16(af, readB<256>(Bs, c, l16, quad, k0), acc[c], 0, 0, 0);
        }
#pragma unroll
        for (int c = 0; c < 4; c++) {
            int col = col0 + 16 * c + l16;
            float bb = bq[col];
#pragma unroll
            for (int r = 0; r < 4; r++) {
                int row = row0 + wave * 16 + quad * 4 + r;
                q_g[(size_t)row * D_ + col] = f2us((acc[c][r] + bb) * QSCALE_);
            }
        }
    } else {
        const int bid = (int)blockIdx.x - 512;
        const int row0 = (bid >> 2) * 64;
        const int col0 = (bid & 3) * 64;
        const float* arow = voxel + (size_t)(row0 + wave * 16 + l16) * D_;

        float4_t ak[4], av[4];
#pragma unroll
        for (int c = 0; c < 4; c++) {
            ak[c] = (float4_t){0.f, 0.f, 0.f, 0.f};
            av[c] = (float4_t){0.f, 0.f, 0.f, 0.f};
        }
        stageB<256, 64>(Wk, col0, Bs, tid);
        __syncthreads();
#pragma unroll
        for (int k0 = 0; k0 < 256; k0 += 32) {
            short8_t af = cvt8(*(const float4*)(arow + k0 + quad * 8),
                               *(const float4*)(arow + k0 + quad * 8 + 4));
#pragma unroll
            for (int c = 0; c < 4; c++)
                ak[c] = __builtin_amdgcn_mfma_f32_16x16x32_bf16(af, readB<256>(Bs, c, l16, quad, k0), ak[c], 0, 0, 0);
        }
        __syncthreads();
        stageB<256, 64>(Wv, col0, Bs, tid);
        __syncthreads();
#pragma unroll
        for (int k0 = 0; k0 < 256; k0 += 32) {
            short8_t af = cvt8(*(const float4*)(arow + k0 + quad * 8),
                               *(const float4*)(arow + k0 + quad * 8 + 4));
#pragma unroll
            for (int c = 0; c < 4; c++)
                av[c] = __builtin_amdgcn_mfma_f32_16x16x32_bf16(af, readB<256>(Bs, c, l16, quad, k0), av[c], 0, 0, 0);
        }
        const int b = row0 / M_;
        const int m0 = row0 - b * M_ + wave * 16 + quad * 4;
#pragma unroll
        for (int c = 0; c < 4; c++) {
            int col = col0 + 16 * c + l16;
            float bbk = bk[col], bbv = bv[col];
#pragma unroll
            for (int r = 0; r < 4; r++) {
                int row = row0 + wave * 16 + quad * 4 + r;
                k_g[(size_t)row * D_ + col] = f2us(ak[c][r] + bbk);
            }
            int h = col >> 5, dh = col & 31;
            unsigned int u0 = pack2rn(av[c][0] + bbv, av[c][1] + bbv);
            unsigned int u1 = pack2rn(av[c][2] + bbv, av[c][3] + bbv);
            *(uint2*)(vt_g + (size_t)((b * H_ + h) * DH_ + dh) * M_ + m0) = make_uint2(u0, u1);
        }
    }
}

// ---------------------------------------------------------------------------
// MFMA flash attention, cooperative dbuf staging, native __expf softmax.
// MODE 0: grid 1024, full kv range, normalized bf16 att out.
// MODE 1: grid 2048, kv-split x2 (half = bid&1, 16 steps each — r14 bug was
//         NSTEP=32 here: OOB kv walk + double-count); writes UNNORMALIZED
//         bf16 O partial + fp32 l partial; combine folded into g_fuse.
// ---------------------------------------------------------------------------
template<int MODE>
__global__ __launch_bounds__(256) void k_attn7(
    const unsigned short* __restrict__ q_g,
    const unsigned short* __restrict__ k_g,
    const unsigned short* __restrict__ vt_g,
    unsigned short* __restrict__ o0_g,
    unsigned short* __restrict__ o1_g,
    float* __restrict__ lsum)
{
    const int tid = threadIdx.x;
    const int w = tid >> 6, lane = tid & 63, quad = lane >> 4, l16 = lane & 15;
    const int bid = blockIdx.x;
    const int half = (MODE == 1) ? (bid & 1) : 0;
    const int rest = (MODE == 1) ? (bid >> 1) : bid;
    const int nt = rest & 63;
    const int bh = rest >> 6;
    const int b = bh >> 3, h = bh & 7;
    const int n0 = nt * 64 + w * 16;
    const int kvbeg = half * (M_ / 2);
    const int NSTEP = (MODE == 1) ? (M_ / 128) : (M_ / 64);  // 16 or 32

    __shared__ unsigned short Kt[2][64][40];
    __shared__ unsigned short Vt[2][32][72];
    __shared__ unsigned short Pb[4][16][64];

    short8_t qf = *(const short8_t*)(q_g + (size_t)(b * N_ + n0 + l16) * D_ + h * DH_ + quad * 8);

    float4_t od0 = {0.f, 0.f, 0.f, 0.f};
    float4_t od1 = {0.f, 0.f, 0.f, 0.f};
    float l_lane = 0.f;

    const unsigned short* kbase = k_g + (size_t)(b * M_) * D_ + h * DH_;
    const unsigned short* vbase = vt_g + (size_t)(bh * DH_) * M_;
    unsigned short* pb = &Pb[w][0][0];
    const int h7 = l16 & 7;
    const float4_t zc = {-ZB_, -ZB_, -ZB_, -ZB_};

    const int kr = tid >> 2, kc = tid & 3;
    const int vr = tid >> 3, vc = tid & 7;

    *(short8_t*)&Kt[0][kr][kc * 8] = *(const short8_t*)(kbase + (size_t)(kvbeg + kr) * D_ + kc * 8);
    *(short8_t*)&Vt[0][vr][vc * 8] = *(const short8_t*)(vbase + (size_t)vr * M_ + kvbeg + vc * 8);

    for (int s = 0; s < NSTEP; s++) {
        __syncthreads();
        const int buf = s & 1;
        const int kv0 = kvbeg + s * 64;
        if (s + 1 < NSTEP) {
            const int kv1 = kv0 + 64;
            *(short8_t*)&Kt[buf ^ 1][kr][kc * 8] =
                *(const short8_t*)(kbase + (size_t)(kv1 + kr) * D_ + kc * 8);
            *(short8_t*)&Vt[buf ^ 1][vr][vc * 8] =
                *(const short8_t*)(vbase + (size_t)vr * M_ + kv1 + vc * 8);
        }

        float4_t st[4];
#pragma unroll
        for (int t = 0; t < 4; t++) {
            short8_t kf = *(const short8_t*)&Kt[buf][16 * t + l16][quad * 8];
            st[t] = __builtin_amdgcn_mfma_f32_16x16x32_bf16(kf, qf, zc, 0, 0, 0);
        }

        float psum = 0.f;
#pragma unroll
        for (int t = 0; t < 4; t++) {
            float p0 = __expf(st[t][0]);
            float p1 = __expf(st[t][1]);
            float p2 = __expf(st[t][2]);
            float p3 = __expf(st[t][3]);
            psum += (p0 + p1) + (p2 + p3);
            unsigned int u0 = pack2tr(p0, p1);
            unsigned int u1 = pack2tr(p2, p3);
            int phys = (2 * t + (quad >> 1)) ^ h7;
            *(uint2*)(pb + l16 * 64 + phys * 8 + (quad & 1) * 4) = make_uint2(u0, u1);
        }
        l_lane += psum;

        short8_t pfa = *(const short8_t*)(pb + l16 * 64 + (quad ^ h7) * 8);
        short8_t pfb = *(const short8_t*)(pb + l16 * 64 + ((4 + quad) ^ h7) * 8);

        short8_t vf00 = *(const short8_t*)&Vt[buf][l16][quad * 8];
        short8_t vf01 = *(const short8_t*)&Vt[buf][l16][32 + quad * 8];
        short8_t vf10 = *(const short8_t*)&Vt[buf][16 + l16][quad * 8];
        short8_t vf11 = *(const short8_t*)&Vt[buf][16 + l16][32 + quad * 8];
        od0 = __builtin_amdgcn_mfma_f32_16x16x32_bf16(vf00, pfa, od0, 0, 0, 0);
        od0 = __builtin_amdgcn_mfma_f32_16x16x32_bf16(vf01, pfb, od0, 0, 0, 0);
        od1 = __builtin_amdgcn_mfma_f32_16x16x32_bf16(vf10, pfa, od1, 0, 0, 0);
        od1 = __builtin_amdgcn_mfma_f32_16x16x32_bf16(vf11, pfb, od1, 0, 0, 0);
    }

    l_lane += __shfl_xor(l_lane, 16);
    l_lane += __shfl_xor(l_lane, 32);

    if (MODE == 0) {
        const float inv = 1.0f / l_lane;
        unsigned short* ob = o0_g + (size_t)(b * N_ + n0 + l16) * D_ + h * DH_;
        unsigned int u0 = pack2rn(od0[0] * inv, od0[1] * inv);
        unsigned int u1 = pack2rn(od0[2] * inv, od0[3] * inv);
        *(uint2*)(ob + quad * 4) = make_uint2(u0, u1);
        unsigned int u2 = pack2rn(od1[0] * inv, od1[1] * inv);
        unsigned int u3 = pack2rn(od1[2] * inv, od1[3] * inv);
        *(uint2*)(ob + 16 + quad * 4) = make_uint2(u2, u3);
    } else {
        const int row = b * N_ + n0 + l16;
        if (quad == 0) lsum[(size_t)half * ROWS_ * H_ + (size_t)row * H_ + h] = l_lane;
        unsigned short* ob = (half ? o1_g : o0_g) + (size_t)row * D_ + h * DH_;
        unsigned int u0 = pack2rn(od0[0], od0[1]);
        unsigned int u1 = pack2rn(od0[2], od0[3]);
        *(uint2*)(ob + quad * 4) = make_uint2(u0, u1);
        unsigned int u2 = pack2rn(od1[0], od1[1]);
        unsigned int u3 = pack2rn(od1[2], od1[3]);
        *(uint2*)(ob + 16 + quad * 4) = make_uint2(u2, u3);
    }
}

// ---------------------------------------------------------------------------
// MFMA GEMM: out = concat(pf, att) @ Wf.T + bf, fp32 out. 64x32 tiles.
// MODE 1: att A-frags combined inline from partials: (o0+o1)/(l0+l1).
// ---------------------------------------------------------------------------
template<int MODE>
__global__ __launch_bounds__(256) void g_fuse(
    const unsigned short* __restrict__ pf_g,
    const unsigned short* __restrict__ o0_g,
    const unsigned short* __restrict__ o1_g,
    const float* __restrict__ lsum,
    const float* __restrict__ Wf, const float* __restrict__ bfb,
    float* __restrict__ out)
{
    const int tid = threadIdx.x;
    const int wave = tid >> 6, lane = tid & 63, quad = lane >> 4, l16 = lane & 15;
    const int row0 = ((int)blockIdx.x >> 3) * 64;
    const int col0 = ((int)blockIdx.x & 7) * 32;

    __shared__ unsigned short Bs[32 * 512];  // 32 KB

    stageB<512, 32>(Wf, col0, Bs, tid);
    __syncthreads();

    float4_t acc[2];
#pragma unroll
    for (int c = 0; c < 2; c++) acc[c] = (float4_t){0.f, 0.f, 0.f, 0.f};

    const int arow_i = row0 + wave * 16 + l16;
    const size_t arow = (size_t)arow_i * D_;
#pragma unroll
    for (int k0 = 0; k0 < 512; k0 += 32) {
        short8_t af;
        if (k0 < 256) {
            af = *(const short8_t*)(pf_g + arow + k0 + quad * 8);
        } else if (MODE == 0) {
            af = *(const short8_t*)(o0_g + arow + (k0 - 256) + quad * 8);
        } else {
            const int co = k0 - 256 + quad * 8;
            const int h = (k0 - 256) >> 5;
            short8_t a0 = *(const short8_t*)(o0_g + arow + co);
            short8_t a1 = *(const short8_t*)(o1_g + arow + co);
            float l0 = lsum[(size_t)arow_i * H_ + h];
            float l1 = lsum[(size_t)ROWS_ * H_ + (size_t)arow_i * H_ + h];
            float inv = 1.0f / (l0 + l1);
            float v[8];
#pragma unroll
            for (int j = 0; j < 8; j++)
                v[j] = (us2f((unsigned short)a0[j]) + us2f((unsigned short)a1[j])) * inv;
            af = cvt8tr(v);
        }
#pragma unroll
        for (int c = 0; c < 2; c++)
            acc[c] = __builtin_amdgcn_mfma_f32_16x16x32_bf16(af, readB<512>(Bs, c, l16, quad, k0), acc[c], 0, 0, 0);
    }
#pragma unroll
    for (int c = 0; c < 2; c++) {
        int col = col0 + 16 * c + l16;
        float bb = bfb[col];
#pragma unroll
        for (int r = 0; r < 4; r++) {
            int row = row0 + wave * 16 + quad * 4 + r;
            out[(size_t)row * D_ + col] = acc[c][r] + bb;
        }
    }
}

// ---------------------------------------------------------------------------
extern "C" void kernel_launch(void* const* d_in, const int* in_sizes, int n_in,
                              void* d_out, int out_size, void* d_ws, size_t ws_size,
                              hipStream_t stream)
{
    const float* points = (const float*)d_in[0];
    const float* voxel  = (const float*)d_in[1];
    const float* Wp  = (const float*)d_in[2];
    const float* bp  = (const float*)d_in[3];
    const float* Wq  = (const float*)d_in[4];
    const float* bq  = (const float*)d_in[5];
    const float* Wk  = (const float*)d_in[6];
    const float* bk  = (const float*)d_in[7];
    const float* Wv  = (const float*)d_in[8];
    const float* bv  = (const float*)d_in[9];
    const float* Wf  = (const float*)d_in[10];
    const float* bfb = (const float*)d_in[11];
    float* out = (float*)d_out;

    unsigned short* ws = (unsigned short*)d_ws;
    unsigned short* pf_g = ws;                               // ROWS*D
    unsigned short* q_g  = pf_g + (size_t)ROWS_ * D_;
    unsigned short* k_g  = q_g  + (size_t)ROWS_ * D_;
    unsigned short* vt_g = k_g  + (size_t)KVROWS_ * D_;
    unsigned short* o0_g = vt_g + (size_t)KVROWS_ * D_;      // att or partial 0
    unsigned short* o1_g = o0_g + (size_t)ROWS_ * D_;        // partial 1 (split)
    float* lsum = (float*)(o1_g + (size_t)ROWS_ * D_);       // [2][ROWS][H]

    const size_t need_split = ((size_t)ROWS_ * D_ * 4 + (size_t)KVROWS_ * D_ * 2) * 2
                            + (size_t)ROWS_ * H_ * 2 * sizeof(float);

    g_proj<<<dim3(768), dim3(256), 0, stream>>>(points, voxel, Wp, bp, Wq, bq,
                                                Wk, bk, Wv, bv, pf_g, q_g, k_g, vt_g);
    if (ws_size >= need_split) {
        k_attn7<1><<<dim3(2 * B_ * H_ * (N_ / 64)), dim3(256), 0, stream>>>(
            q_g, k_g, vt_g, o0_g, o1_g, lsum);
        g_fuse<1><<<dim3((ROWS_ / 64) * 8), dim3(256), 0, stream>>>(
            pf_g, o0_g, o1_g, lsum, Wf, bfb, out);
    } else {
        k_attn7<0><<<dim3(B_ * H_ * (N_ / 64)), dim3(256), 0, stream>>>(
            q_g, k_g, vt_g, o0_g, o1_g, lsum);
        g_fuse<0><<<dim3((ROWS_ / 64) * 8), dim3(256), 0, stream>>>(
            pf_g, o0_g, o1_g, lsum, Wf, bfb, out);
    }
}